// Round 1
// baseline (14229.401 us; speedup 1.0000x reference)
//
#include <hip/hip_runtime.h>
#include <hip/hip_bf16.h>
#include <hip/hip_cooperative_groups.h>

namespace cg = cooperative_groups;

// Bidirectional 4-layer residual LSTM encoder, MI355X (gfx950).
// R4: persistent cooperative kernel. Weights (64 MB bf16 = half the chip's
// 128 MB RF) pinned in VGPRs: wave w of block (layer,cb) holds a 64-row x
// 256-K slice = 128 VGPRs, loaded ONCE. One grid.sync() per diagonal step
// replaces 259 kernel launches + 16.6 GB of per-step weight re-streaming.
// Dirs processed sequentially (acc reused) to fit the 256-VGPR/wave cap at
// 8 waves/CU. Cross-wave K-partial reduction via transposed XOR-swizzled
// LDS (f32x4 ds_write_b128, uniform banks). c-state lives in registers.

typedef __bf16 bf16x8 __attribute__((ext_vector_type(8)));
typedef __bf16 bf16x4 __attribute__((ext_vector_type(4)));
typedef float  f32x4  __attribute__((ext_vector_type(4)));

constexpr int NB = 64;    // batch
constexpr int NT = 256;   // time
constexpr int ND = 1024;  // embed dim
constexpr int NH = 1024;  // hidden
constexpr int NL = 4;     // layers
constexpr int NG = 4096;  // 4*NH gate rows

// ---------------------------------------------------------------------------
// Persistent kernel. Grid: 4 layers x 64 cb = 256 blocks (1/CU, forced by
// 128 KB LDS). Block: 512 threads = 8 waves. Wave w: mat = w>>2 (0: Wih,
// 1: Whh), k0 = (w&3)*256 (K-slice). Weight regs: bf16x8 wreg[4 gates][8 ch].
// Per step, per dir: acc[4 m][4 n] over M=64 batch x N=64 gate-cols,
// partials -> gbuf[w][gate][col16][row64 ^ swz] -> pointwise LSTM.
// C/D frag (m89): row(batch)=(l>>4)*4+r (+16m), col=l&15.
// ---------------------------------------------------------------------------
__global__ __launch_bounds__(512, 2) void k_lstm(
    const __bf16* __restrict__ xbf,     // [NT][NB][ND]
    const __bf16* __restrict__ Wih,     // [NL][NG][ND] bf16
    const __bf16* __restrict__ Whh,     // [NL][NG][NH] bf16
    const float*  __restrict__ biasc,   // [NL][NG] (b_ih+b_hh)
    __bf16* __restrict__ ring_b,        // [2*NL][2][NB][NH] layer input (bf16)
    float*  __restrict__ ring_f,        // [2*NL][2][NB][NH] layer input (f32)
    __bf16* __restrict__ hbuf,          // [2*NL][2][NB][NH] h ping-pong
    __bf16* __restrict__ outcat,        // [NT][NB][2*NH]
    __bf16* __restrict__ hcat,          // [NL*NB][2*NH] final h
    __bf16* __restrict__ ccat)          // [NL*NB][2*NH] final c
{
    const int layer = blockIdx.x >> 6;   // 0..3
    const int cb    = blockIdx.x & 63;   // 16 H-cols each
    const int tid   = threadIdx.x;
    const int w     = tid >> 6;          // 0..7
    const int mat   = w >> 2;            // 0: x-part (Wih), 1: h-part (Whh)
    const int k0    = (w & 3) * 256;     // K-slice within the 1024 of this mat
    const int lane  = tid & 63;
    const int lrow  = lane & 15;
    const int lk    = (lane >> 4) << 3;
    const int g4r   = (lane >> 4) << 2;  // row base within 16-row frag
    const size_t bh = (size_t)NB * NH;

    // --- persistent weights: 64 rows x 256 K bf16 = 128 VGPRs/wave ---
    bf16x8 wreg[4][8];
    {
        const __bf16* Bp = (mat ? Whh : Wih)
            + ((size_t)layer * NG + cb * 16 + lrow) * 1024 + k0 + lk;
        #pragma unroll
        for (int n = 0; n < 4; ++n)
            #pragma unroll
            for (int ch = 0; ch < 8; ++ch)
                wreg[n][ch] = *(const bf16x8*)(Bp + (size_t)n * NH * 1024 + ch * 32);
    }

    // --- per-thread persistent bias (n = tid&15 is this thread's col) ---
    float bias4[4];
    #pragma unroll
    for (int g = 0; g < 4; ++g)
        bias4[g] = biasc[(size_t)layer * NG + g * NH + cb * 16 + (tid & 15)];

    // --- per-thread persistent c state: [d][half], static mapping ---
    float c00 = 0.f, c01 = 0.f, c10 = 0.f, c11 = 0.f;

    // transposed partial buffer: [wave][gate][col16][row64], rows XOR-swizzled
    __shared__ __align__(16) float gbuf[8][4][16][64];   // 128 KB

    cg::grid_group grid = cg::this_grid();

    for (int gs = 0; gs < NT + NL - 1; ++gs) {
        const int tau = gs - layer;
        if (tau >= 0 && tau < NT) {
            #pragma unroll 1
            for (int d = 0; d < 2; ++d) {
                const int tt = d ? NT - 1 - tau : tau;
                const size_t ul = (size_t)(d * NL + layer);

                // A pointer for this wave's mat
                const __bf16* Ap;
                if (mat == 0)
                    Ap = (layer == 0) ? (xbf + (size_t)tt * NB * ND)
                                      : (ring_b + (ul * 2 + (tau & 1)) * bh);
                else
                    Ap = hbuf + (ul * 2 + ((tau + 1) & 1)) * bh;
                Ap += (size_t)lrow * 1024 + k0 + lk;

                f32x4 acc[4][4] = {};   // [m][gate]
                #pragma unroll
                for (int ch = 0; ch < 8; ++ch) {
                    bf16x8 av[4];
                    #pragma unroll
                    for (int m = 0; m < 4; ++m)
                        av[m] = *(const bf16x8*)(Ap + (size_t)m * 16 * 1024 + ch * 32);
                    #pragma unroll
                    for (int n = 0; n < 4; ++n)
                        #pragma unroll
                        for (int m = 0; m < 4; ++m)
                            acc[m][n] = __builtin_amdgcn_mfma_f32_16x16x32_bf16(
                                av[m], wreg[n][ch], acc[m][n], 0, 0, 0);
                }

                // partials -> LDS as f32x4 (4 consecutive batch rows), swizzled
                #pragma unroll
                for (int n = 0; n < 4; ++n)
                    #pragma unroll
                    for (int m = 0; m < 4; ++m) {
                        const int row = (m * 16 + g4r) ^ ((lrow & 7) << 2);
                        *(f32x4*)&gbuf[w][n][lrow][row] = acc[m][n];
                    }
                __syncthreads();

                // fused LSTM pointwise: 2 cells/thread (n fixed = tid&15)
                #pragma unroll
                for (int half = 0; half < 2; ++half) {
                    const int b   = (half << 5) + (tid >> 4);
                    const int n   = tid & 15;
                    const int col = cb * 16 + n;
                    const int swb = b ^ ((n & 7) << 2);
                    float g4[4];
                    #pragma unroll
                    for (int g = 0; g < 4; ++g) {
                        float s = bias4[g];
                        #pragma unroll
                        for (int q = 0; q < 8; ++q) s += gbuf[q][g][n][swb];
                        g4[g] = s;
                    }
                    const float ig = g4[0], fg = g4[1], gg = g4[2], og = g4[3];
                    const float cprev = d ? (half ? c11 : c10) : (half ? c01 : c00);
                    const float si = 1.f / (1.f + __expf(-ig));
                    const float sf = 1.f / (1.f + __expf(-fg));
                    const float so = 1.f / (1.f + __expf(-og));
                    const float tg = tanhf(gg);
                    const float cn = sf * cprev + si * tg;
                    const float hn = so * tanhf(cn);
                    if (d) { if (half) c11 = cn; else c10 = cn; }
                    else   { if (half) c01 = cn; else c00 = cn; }
                    hbuf[(ul * 2 + (tau & 1)) * bh + (size_t)b * NH + col] = (__bf16)hn;

                    float inpv;
                    if (layer == 0)
                        inpv = (float)xbf[(size_t)tt * NB * ND + (size_t)b * ND + col];
                    else
                        inpv = ring_f[(ul * 2 + (tau & 1)) * bh + (size_t)b * NH + col];
                    const float nv = inpv + hn;
                    if (layer < NL - 1) {
                        const size_t ri = ((ul + 1) * 2 + (tau & 1)) * bh + (size_t)b * NH + col;
                        ring_f[ri] = nv;
                        ring_b[ri] = (__bf16)nv;
                    } else {
                        outcat[((size_t)tt * NB + b) * (2 * NH) + (size_t)d * NH + col] = (__bf16)nv;
                    }
                    if (tau == NT - 1) {
                        const size_t fr = ((size_t)layer * NB + b) * (2 * NH) + (size_t)d * NH + col;
                        hcat[fr] = (__bf16)hn;
                        ccat[fr] = (__bf16)cn;
                    }
                }
                __syncthreads();
            }
        }
        grid.sync();
    }
}

// ---------------------------------------------------------------------------
// Projection GEMM: Dst = A[M][2048] @ W[1024][2048]^T + bias.
// mode 0: A rows are (t*NB+b), write Dst[(b*NT+t)*NH + col]. mode 1: direct.
// ---------------------------------------------------------------------------
__global__ __launch_bounds__(256) void k_proj(
    const __bf16* __restrict__ A, const __bf16* __restrict__ W,
    const float* __restrict__ bias, float* __restrict__ Dst,
    int M, int mode)
{
    const int nblk = blockIdx.x & 15;
    const int mblk = blockIdx.x >> 4;
    const int tid  = threadIdx.x;
    const int w    = tid >> 6;
    const int lane = tid & 63;
    const int lrow = lane & 15;
    const int lk   = (lane >> 4) << 3;
    const int n0   = nblk * 64 + w * 16;
    const int m0   = mblk * 64;

    f32x4 acc[4] = {};
    #pragma unroll 2
    for (int k0 = 0; k0 < 2048; k0 += 32) {
        const int kc = k0 + lk;
        const bf16x8 bv = *(const bf16x8*)(W + (size_t)(n0 + lrow) * 2048 + kc);
        #pragma unroll
        for (int m = 0; m < 4; ++m) {
            const bf16x8 av = *(const bf16x8*)(A + (size_t)(m0 + m * 16 + lrow) * 2048 + kc);
            acc[m] = __builtin_amdgcn_mfma_f32_16x16x32_bf16(av, bv, acc[m], 0, 0, 0);
        }
    }
    #pragma unroll
    for (int m = 0; m < 4; ++m) {
        #pragma unroll
        for (int r = 0; r < 4; ++r) {
            const int row = m0 + m * 16 + ((lane >> 4) << 2) + r;
            const int col = n0 + lrow;
            const float v = acc[m][r] + bias[col];
            if (mode == 0) {
                const int tt = row >> 6, bb = row & 63;
                Dst[((size_t)bb * NT + tt) * NH + col] = v;
            } else {
                Dst[(size_t)row * NH + col] = v;
            }
        }
    }
}

__global__ void k_embed(const int* __restrict__ enc, const float* __restrict__ emb,
                        __bf16* __restrict__ xbf)
{
    const int r = blockIdx.x;          // t*NB + b
    const int t = r >> 6;
    const int b = r & 63;
    const int id = enc[b * NT + t];
    const float4 v = ((const float4*)(emb + (size_t)id * ND))[threadIdx.x];
    bf16x4 o;
    o[0] = (__bf16)v.x; o[1] = (__bf16)v.y; o[2] = (__bf16)v.z; o[3] = (__bf16)v.w;
    ((bf16x4*)(xbf + (size_t)r * ND))[threadIdx.x] = o;
}

__global__ void k_cvt(const float* __restrict__ src, __bf16* __restrict__ dst, size_t n4)
{
    size_t i = (size_t)blockIdx.x * blockDim.x + threadIdx.x;
    const size_t stride = (size_t)gridDim.x * blockDim.x;
    for (; i < n4; i += stride) {
        const float4 v = ((const float4*)src)[i];
        bf16x4 o;
        o[0] = (__bf16)v.x; o[1] = (__bf16)v.y; o[2] = (__bf16)v.z; o[3] = (__bf16)v.w;
        ((bf16x4*)dst)[i] = o;
    }
}

__global__ void k_bias(const float* __restrict__ a, const float* __restrict__ b,
                       float* __restrict__ o, int n)
{
    const int i = blockIdx.x * blockDim.x + threadIdx.x;
    if (i < n) o[i] = a[i] + b[i];
}

extern "C" void kernel_launch(void* const* d_in, const int* in_sizes, int n_in,
                              void* d_out, int out_size, void* d_ws, size_t ws_size,
                              hipStream_t stream)
{
    const int*   enc   = (const int*)  d_in[0];
    const float* emb   = (const float*)d_in[1];
    const float* Wih_f = (const float*)d_in[2];
    const float* Whh_f = (const float*)d_in[3];
    const float* bih   = (const float*)d_in[4];
    const float* bhh   = (const float*)d_in[5];
    const float* Wo_f  = (const float*)d_in[6];
    const float* bo    = (const float*)d_in[7];
    const float* Wh_f  = (const float*)d_in[8];
    const float* bh    = (const float*)d_in[9];
    const float* Wc_f  = (const float*)d_in[10];
    const float* bc    = (const float*)d_in[11];
    float* out = (float*)d_out;

    char* ws = (char*)d_ws;
    size_t off = 0;
    auto alloc = [&](size_t bytes) -> char* {
        off = (off + 255) & ~(size_t)255;
        char* p = ws + off;
        off += bytes;
        return p;
    };
    __bf16* Wih_b  = (__bf16*)alloc((size_t)NL * NG * ND * 2);
    __bf16* Whh_b  = (__bf16*)alloc((size_t)NL * NG * NH * 2);
    __bf16* Wo_b   = (__bf16*)alloc((size_t)NH * 2 * NH * 2);
    __bf16* Wh_b   = (__bf16*)alloc((size_t)NH * 2 * NH * 2);
    __bf16* Wc_b   = (__bf16*)alloc((size_t)NH * 2 * NH * 2);
    float*  biasc  = (float*) alloc((size_t)NL * NG * 4);
    __bf16* xbf    = (__bf16*)alloc((size_t)NT * NB * ND * 2);
    __bf16* ring_b = (__bf16*)alloc((size_t)2 * NL * 2 * NB * NH * 2);
    float*  ring_f = (float*) alloc((size_t)2 * NL * 2 * NB * NH * 4);
    __bf16* hbuf   = (__bf16*)alloc((size_t)2 * NL * 2 * NB * NH * 2);
    __bf16* outcat = (__bf16*)alloc((size_t)NT * NB * 2 * NH * 2);
    __bf16* hcat   = (__bf16*)alloc((size_t)NL * NB * 2 * NH * 2);
    __bf16* ccat   = (__bf16*)alloc((size_t)NL * NB * 2 * NH * 2);

    auto launch_cvt = [&](const float* s, __bf16* d, size_t n) {
        size_t n4 = n / 4;
        int blocks = (int)((n4 + 255) / 256);
        if (blocks > 2048) blocks = 2048;
        k_cvt<<<blocks, 256, 0, stream>>>(s, d, n4);
    };
    launch_cvt(Wih_f, Wih_b, (size_t)NL * NG * ND);
    launch_cvt(Whh_f, Whh_b, (size_t)NL * NG * NH);
    launch_cvt(Wo_f,  Wo_b,  (size_t)2 * NH * NH);
    launch_cvt(Wh_f,  Wh_b,  (size_t)2 * NH * NH);
    launch_cvt(Wc_f,  Wc_b,  (size_t)2 * NH * NH);
    k_bias<<<(NL * NG) / 256, 256, 0, stream>>>(bih, bhh, biasc, NL * NG);
    k_embed<<<NT * NB, 256, 0, stream>>>(enc, emb, xbf);
    // h state must be zeroed EVERY launch (graph replays leave final state);
    // c state is register-resident and fresh per launch.
    hipMemsetAsync(hbuf, 0, (size_t)2 * NL * 2 * NB * NH * 2, stream);

    void* kargs[] = {
        (void*)&xbf, (void*)&Wih_b, (void*)&Whh_b, (void*)&biasc,
        (void*)&ring_b, (void*)&ring_f, (void*)&hbuf,
        (void*)&outcat, (void*)&hcat, (void*)&ccat };
    hipLaunchCooperativeKernel((const void*)k_lstm, dim3(256), dim3(512),
                               kargs, 0, stream);

    k_proj<<<(NT * NB / 64) * 16, 256, 0, stream>>>(outcat, Wo_b, bo, out, NT * NB, 0);
    k_proj<<<(NL * NB / 64) * 16, 256, 0, stream>>>(hcat, Wh_b, bh,
        out + (size_t)NB * NT * NH, NL * NB, 1);
    k_proj<<<(NL * NB / 64) * 16, 256, 0, stream>>>(ccat, Wc_b, bc,
        out + (size_t)NB * NT * NH + (size_t)NL * NB * NH, NL * NB, 1);
}

// Round 2
// 9965.726 us; speedup vs baseline: 1.4278x; 1.4278x over previous
//
#include <hip/hip_runtime.h>
#include <hip/hip_bf16.h>

// Bidirectional 4-layer residual LSTM encoder, MI355X (gfx950).
// R5: persistent cooperative kernel (weights pinned in VGPR/AGPR, verified
// by R4 FETCH_SIZE = 9.8 MB/step, not 64 MB/step) with grid.sync() replaced
// by a custom two-level agent-scope barrier. R4 showed grid.sync costs
// ~47 us/step (system-scope flush + contended arrival atomic). The custom
// barrier: __threadfence (agent wbl2/inv - the minimal coherence for the
// cross-XCD h/ring exchange) + 16 leaf counters -> root -> monotonic epoch
// release flag in LLC. Everything else identical to R4 (which passed).

typedef __bf16 bf16x8 __attribute__((ext_vector_type(8)));
typedef __bf16 bf16x4 __attribute__((ext_vector_type(4)));
typedef float  f32x4  __attribute__((ext_vector_type(4)));

constexpr int NB = 64;    // batch
constexpr int NT = 256;   // time
constexpr int ND = 1024;  // embed dim
constexpr int NH = 1024;  // hidden
constexpr int NL = 4;     // layers
constexpr int NG = 4096;  // 4*NH gate rows

// ---------------------------------------------------------------------------
// Persistent kernel. Grid: 4 layers x 64 cb = 256 blocks (1/CU, forced by
// 128 KB LDS). Block: 512 threads = 8 waves. Wave w: mat = w>>2 (0: Wih,
// 1: Whh), k0 = (w&3)*256 (K-slice). Weight regs: bf16x8 wreg[4 gates][8 ch].
// Per step, per dir: acc[4 m][4 n] over M=64 batch x N=64 gate-cols,
// partials -> gbuf[w][gate][col16][row64 ^ swz] -> pointwise LSTM.
// C/D frag (m89): row(batch)=(l>>4)*4+r (+16m), col=l&15.
// Barrier layout (uint idx): leaves at 32*(bid&15), root at 512, rel at 544.
// ---------------------------------------------------------------------------
__global__ __launch_bounds__(512, 2) void k_lstm(
    const __bf16* __restrict__ xbf,     // [NT][NB][ND]
    const __bf16* __restrict__ Wih,     // [NL][NG][ND] bf16
    const __bf16* __restrict__ Whh,     // [NL][NG][NH] bf16
    const float*  __restrict__ biasc,   // [NL][NG] (b_ih+b_hh)
    __bf16* __restrict__ ring_b,        // [2*NL][2][NB][NH] layer input (bf16)
    float*  __restrict__ ring_f,        // [2*NL][2][NB][NH] layer input (f32)
    __bf16* __restrict__ hbuf,          // [2*NL][2][NB][NH] h ping-pong
    __bf16* __restrict__ outcat,        // [NT][NB][2*NH]
    __bf16* __restrict__ hcat,          // [NL*NB][2*NH] final h
    __bf16* __restrict__ ccat,          // [NL*NB][2*NH] final c
    unsigned* __restrict__ bar)         // barrier state (zeroed per launch)
{
    const int layer = blockIdx.x >> 6;   // 0..3
    const int cb    = blockIdx.x & 63;   // 16 H-cols each
    const int tid   = threadIdx.x;
    const int w     = tid >> 6;          // 0..7
    const int mat   = w >> 2;            // 0: x-part (Wih), 1: h-part (Whh)
    const int k0    = (w & 3) * 256;     // K-slice within the 1024 of this mat
    const int lane  = tid & 63;
    const int lrow  = lane & 15;
    const int lk    = (lane >> 4) << 3;
    const int g4r   = (lane >> 4) << 2;  // row base within 16-row frag
    const size_t bh = (size_t)NB * NH;

    // --- persistent weights: 64 rows x 256 K bf16 = 128 VGPRs/wave ---
    bf16x8 wreg[4][8];
    {
        const __bf16* Bp = (mat ? Whh : Wih)
            + ((size_t)layer * NG + cb * 16 + lrow) * 1024 + k0 + lk;
        #pragma unroll
        for (int n = 0; n < 4; ++n)
            #pragma unroll
            for (int ch = 0; ch < 8; ++ch)
                wreg[n][ch] = *(const bf16x8*)(Bp + (size_t)n * NH * 1024 + ch * 32);
    }

    // --- per-thread persistent bias (n = tid&15 is this thread's col) ---
    float bias4[4];
    #pragma unroll
    for (int g = 0; g < 4; ++g)
        bias4[g] = biasc[(size_t)layer * NG + g * NH + cb * 16 + (tid & 15)];

    // --- per-thread persistent c state: [d][half], static mapping ---
    float c00 = 0.f, c01 = 0.f, c10 = 0.f, c11 = 0.f;

    // transposed partial buffer: [wave][gate][col16][row64], rows XOR-swizzled
    __shared__ __align__(16) float gbuf[8][4][16][64];   // 128 KB

    unsigned* leaf = bar + 32 * (blockIdx.x & 15);
    unsigned* root = bar + 512;
    unsigned* rel  = bar + 544;

    for (int gs = 0; gs < NT + NL - 1; ++gs) {
        const int tau = gs - layer;
        if (tau >= 0 && tau < NT) {
            #pragma unroll 1
            for (int d = 0; d < 2; ++d) {
                const int tt = d ? NT - 1 - tau : tau;
                const size_t ul = (size_t)(d * NL + layer);

                // A pointer for this wave's mat
                const __bf16* Ap;
                if (mat == 0)
                    Ap = (layer == 0) ? (xbf + (size_t)tt * NB * ND)
                                      : (ring_b + (ul * 2 + (tau & 1)) * bh);
                else
                    Ap = hbuf + (ul * 2 + ((tau + 1) & 1)) * bh;
                Ap += (size_t)lrow * 1024 + k0 + lk;

                f32x4 acc[4][4] = {};   // [m][gate]
                #pragma unroll
                for (int ch = 0; ch < 8; ++ch) {
                    bf16x8 av[4];
                    #pragma unroll
                    for (int m = 0; m < 4; ++m)
                        av[m] = *(const bf16x8*)(Ap + (size_t)m * 16 * 1024 + ch * 32);
                    #pragma unroll
                    for (int n = 0; n < 4; ++n)
                        #pragma unroll
                        for (int m = 0; m < 4; ++m)
                            acc[m][n] = __builtin_amdgcn_mfma_f32_16x16x32_bf16(
                                av[m], wreg[n][ch], acc[m][n], 0, 0, 0);
                }

                // partials -> LDS as f32x4 (4 consecutive batch rows), swizzled
                #pragma unroll
                for (int n = 0; n < 4; ++n)
                    #pragma unroll
                    for (int m = 0; m < 4; ++m) {
                        const int row = (m * 16 + g4r) ^ ((lrow & 7) << 2);
                        *(f32x4*)&gbuf[w][n][lrow][row] = acc[m][n];
                    }
                __syncthreads();

                // fused LSTM pointwise: 2 cells/thread (n fixed = tid&15)
                #pragma unroll
                for (int half = 0; half < 2; ++half) {
                    const int b   = (half << 5) + (tid >> 4);
                    const int n   = tid & 15;
                    const int col = cb * 16 + n;
                    const int swb = b ^ ((n & 7) << 2);
                    float g4[4];
                    #pragma unroll
                    for (int g = 0; g < 4; ++g) {
                        float s = bias4[g];
                        #pragma unroll
                        for (int q = 0; q < 8; ++q) s += gbuf[q][g][n][swb];
                        g4[g] = s;
                    }
                    const float ig = g4[0], fg = g4[1], gg = g4[2], og = g4[3];
                    const float cprev = d ? (half ? c11 : c10) : (half ? c01 : c00);
                    const float si = 1.f / (1.f + __expf(-ig));
                    const float sf = 1.f / (1.f + __expf(-fg));
                    const float so = 1.f / (1.f + __expf(-og));
                    const float tg = tanhf(gg);
                    const float cn = sf * cprev + si * tg;
                    const float hn = so * tanhf(cn);
                    if (d) { if (half) c11 = cn; else c10 = cn; }
                    else   { if (half) c01 = cn; else c00 = cn; }
                    hbuf[(ul * 2 + (tau & 1)) * bh + (size_t)b * NH + col] = (__bf16)hn;

                    float inpv;
                    if (layer == 0)
                        inpv = (float)xbf[(size_t)tt * NB * ND + (size_t)b * ND + col];
                    else
                        inpv = ring_f[(ul * 2 + (tau & 1)) * bh + (size_t)b * NH + col];
                    const float nv = inpv + hn;
                    if (layer < NL - 1) {
                        const size_t ri = ((ul + 1) * 2 + (tau & 1)) * bh + (size_t)b * NH + col;
                        ring_f[ri] = nv;
                        ring_b[ri] = (__bf16)nv;
                    } else {
                        outcat[((size_t)tt * NB + b) * (2 * NH) + (size_t)d * NH + col] = (__bf16)nv;
                    }
                    if (tau == NT - 1) {
                        const size_t fr = ((size_t)layer * NB + b) * (2 * NH) + (size_t)d * NH + col;
                        hcat[fr] = (__bf16)hn;
                        ccat[fr] = (__bf16)cn;
                    }
                }
                __syncthreads();
            }
        }

        // ---- custom grid barrier (skip after last step) ----
        if (gs < NT + NL - 2) {
            __syncthreads();               // all waves' stores drained (vmcnt 0)
            if (tid == 0) {
                __threadfence();           // agent fence: wb own XCD L2
                const unsigned e1 = (unsigned)(gs + 1);
                const unsigned old = __hip_atomic_fetch_add(
                    leaf, 1u, __ATOMIC_RELAXED, __HIP_MEMORY_SCOPE_AGENT);
                if (old == 16u * e1 - 1u) {
                    const unsigned r = __hip_atomic_fetch_add(
                        root, 1u, __ATOMIC_RELAXED, __HIP_MEMORY_SCOPE_AGENT);
                    if (r == 16u * e1 - 1u)
                        __hip_atomic_store(rel, e1, __ATOMIC_RELAXED,
                                           __HIP_MEMORY_SCOPE_AGENT);
                }
                while (__hip_atomic_load(rel, __ATOMIC_RELAXED,
                                         __HIP_MEMORY_SCOPE_AGENT) < e1)
                    __builtin_amdgcn_s_sleep(2);
                __threadfence();           // agent fence: inv L1/L2 for fresh reads
            }
            __syncthreads();
        }
    }
}

// ---------------------------------------------------------------------------
// Projection GEMM: Dst = A[M][2048] @ W[1024][2048]^T + bias.
// mode 0: A rows are (t*NB+b), write Dst[(b*NT+t)*NH + col]. mode 1: direct.
// ---------------------------------------------------------------------------
__global__ __launch_bounds__(256) void k_proj(
    const __bf16* __restrict__ A, const __bf16* __restrict__ W,
    const float* __restrict__ bias, float* __restrict__ Dst,
    int M, int mode)
{
    const int nblk = blockIdx.x & 15;
    const int mblk = blockIdx.x >> 4;
    const int tid  = threadIdx.x;
    const int w    = tid >> 6;
    const int lane = tid & 63;
    const int lrow = lane & 15;
    const int lk   = (lane >> 4) << 3;
    const int n0   = nblk * 64 + w * 16;
    const int m0   = mblk * 64;

    f32x4 acc[4] = {};
    #pragma unroll 2
    for (int k0 = 0; k0 < 2048; k0 += 32) {
        const int kc = k0 + lk;
        const bf16x8 bv = *(const bf16x8*)(W + (size_t)(n0 + lrow) * 2048 + kc);
        #pragma unroll
        for (int m = 0; m < 4; ++m) {
            const bf16x8 av = *(const bf16x8*)(A + (size_t)(m0 + m * 16 + lrow) * 2048 + kc);
            acc[m] = __builtin_amdgcn_mfma_f32_16x16x32_bf16(av, bv, acc[m], 0, 0, 0);
        }
    }
    #pragma unroll
    for (int m = 0; m < 4; ++m) {
        #pragma unroll
        for (int r = 0; r < 4; ++r) {
            const int row = m0 + m * 16 + ((lane >> 4) << 2) + r;
            const int col = n0 + lrow;
            const float v = acc[m][r] + bias[col];
            if (mode == 0) {
                const int tt = row >> 6, bb = row & 63;
                Dst[((size_t)bb * NT + tt) * NH + col] = v;
            } else {
                Dst[(size_t)row * NH + col] = v;
            }
        }
    }
}

__global__ void k_embed(const int* __restrict__ enc, const float* __restrict__ emb,
                        __bf16* __restrict__ xbf)
{
    const int r = blockIdx.x;          // t*NB + b
    const int t = r >> 6;
    const int b = r & 63;
    const int id = enc[b * NT + t];
    const float4 v = ((const float4*)(emb + (size_t)id * ND))[threadIdx.x];
    bf16x4 o;
    o[0] = (__bf16)v.x; o[1] = (__bf16)v.y; o[2] = (__bf16)v.z; o[3] = (__bf16)v.w;
    ((bf16x4*)(xbf + (size_t)r * ND))[threadIdx.x] = o;
}

__global__ void k_cvt(const float* __restrict__ src, __bf16* __restrict__ dst, size_t n4)
{
    size_t i = (size_t)blockIdx.x * blockDim.x + threadIdx.x;
    const size_t stride = (size_t)gridDim.x * blockDim.x;
    for (; i < n4; i += stride) {
        const float4 v = ((const float4*)src)[i];
        bf16x4 o;
        o[0] = (__bf16)v.x; o[1] = (__bf16)v.y; o[2] = (__bf16)v.z; o[3] = (__bf16)v.w;
        ((bf16x4*)dst)[i] = o;
    }
}

__global__ void k_bias(const float* __restrict__ a, const float* __restrict__ b,
                       float* __restrict__ o, int n)
{
    const int i = blockIdx.x * blockDim.x + threadIdx.x;
    if (i < n) o[i] = a[i] + b[i];
}

extern "C" void kernel_launch(void* const* d_in, const int* in_sizes, int n_in,
                              void* d_out, int out_size, void* d_ws, size_t ws_size,
                              hipStream_t stream)
{
    const int*   enc   = (const int*)  d_in[0];
    const float* emb   = (const float*)d_in[1];
    const float* Wih_f = (const float*)d_in[2];
    const float* Whh_f = (const float*)d_in[3];
    const float* bih   = (const float*)d_in[4];
    const float* bhh   = (const float*)d_in[5];
    const float* Wo_f  = (const float*)d_in[6];
    const float* bo    = (const float*)d_in[7];
    const float* Wh_f  = (const float*)d_in[8];
    const float* bh    = (const float*)d_in[9];
    const float* Wc_f  = (const float*)d_in[10];
    const float* bc    = (const float*)d_in[11];
    float* out = (float*)d_out;

    char* ws = (char*)d_ws;
    size_t off = 0;
    auto alloc = [&](size_t bytes) -> char* {
        off = (off + 255) & ~(size_t)255;
        char* p = ws + off;
        off += bytes;
        return p;
    };
    __bf16* Wih_b  = (__bf16*)alloc((size_t)NL * NG * ND * 2);
    __bf16* Whh_b  = (__bf16*)alloc((size_t)NL * NG * NH * 2);
    __bf16* Wo_b   = (__bf16*)alloc((size_t)NH * 2 * NH * 2);
    __bf16* Wh_b   = (__bf16*)alloc((size_t)NH * 2 * NH * 2);
    __bf16* Wc_b   = (__bf16*)alloc((size_t)NH * 2 * NH * 2);
    float*  biasc  = (float*) alloc((size_t)NL * NG * 4);
    __bf16* xbf    = (__bf16*)alloc((size_t)NT * NB * ND * 2);
    __bf16* ring_b = (__bf16*)alloc((size_t)2 * NL * 2 * NB * NH * 2);
    float*  ring_f = (float*) alloc((size_t)2 * NL * 2 * NB * NH * 4);
    __bf16* hbuf   = (__bf16*)alloc((size_t)2 * NL * 2 * NB * NH * 2);
    __bf16* outcat = (__bf16*)alloc((size_t)NT * NB * 2 * NH * 2);
    __bf16* hcat   = (__bf16*)alloc((size_t)NL * NB * 2 * NH * 2);
    __bf16* ccat   = (__bf16*)alloc((size_t)NL * NB * 2 * NH * 2);
    unsigned* bar  = (unsigned*)alloc(4096);

    auto launch_cvt = [&](const float* s, __bf16* d, size_t n) {
        size_t n4 = n / 4;
        int blocks = (int)((n4 + 255) / 256);
        if (blocks > 2048) blocks = 2048;
        k_cvt<<<blocks, 256, 0, stream>>>(s, d, n4);
    };
    launch_cvt(Wih_f, Wih_b, (size_t)NL * NG * ND);
    launch_cvt(Whh_f, Whh_b, (size_t)NL * NG * NH);
    launch_cvt(Wo_f,  Wo_b,  (size_t)2 * NH * NH);
    launch_cvt(Wh_f,  Wh_b,  (size_t)2 * NH * NH);
    launch_cvt(Wc_f,  Wc_b,  (size_t)2 * NH * NH);
    k_bias<<<(NL * NG) / 256, 256, 0, stream>>>(bih, bhh, biasc, NL * NG);
    k_embed<<<NT * NB, 256, 0, stream>>>(enc, emb, xbf);
    // h state + barrier counters must be zeroed EVERY launch (graph replays
    // leave final state; barrier epochs are monotonic within one launch).
    hipMemsetAsync(hbuf, 0, (size_t)2 * NL * 2 * NB * NH * 2, stream);
    hipMemsetAsync(bar, 0, 4096, stream);

    void* kargs[] = {
        (void*)&xbf, (void*)&Wih_b, (void*)&Whh_b, (void*)&biasc,
        (void*)&ring_b, (void*)&ring_f, (void*)&hbuf,
        (void*)&outcat, (void*)&hcat, (void*)&ccat, (void*)&bar };
    hipLaunchCooperativeKernel((const void*)k_lstm, dim3(256), dim3(512),
                               kargs, 0, stream);

    k_proj<<<(NT * NB / 64) * 16, 256, 0, stream>>>(outcat, Wo_b, bo, out, NT * NB, 0);
    k_proj<<<(NL * NB / 64) * 16, 256, 0, stream>>>(hcat, Wh_b, bh,
        out + (size_t)NB * NT * NH, NL * NB, 1);
    k_proj<<<(NL * NB / 64) * 16, 256, 0, stream>>>(ccat, Wc_b, bc,
        out + (size_t)NB * NT * NH + (size_t)NL * NB * NH, NL * NB, 1);
}

// Round 4
// 9484.200 us; speedup vs baseline: 1.5003x; 1.0508x over previous
//
#include <hip/hip_runtime.h>
#include <hip/hip_bf16.h>

// Bidirectional 4-layer residual LSTM encoder, MI355X (gfx950).
// R7: fence-free persistent kernel, CORRECTNESS-HARDENED sc loads.
// R6's NaN fail: deferred asm loads (separate load asm + waitcnt asm) let
// the compiler copy in-flight output regs / insert scratch VMEM that broke
// manual vmcnt counting. R7: every sc load is a SINGLE asm bundle that
// issues 4x global_load_dwordx4 sc0 sc1 and ends with s_waitcnt vmcnt(0)
// (outputs valid at asm exit; spills harmless). Residual f32 reads via
// __hip_atomic_load(SYSTEM) (compiler-tracked). Stores: fire-and-forget
// sc0 sc1 asm + one vmcnt(0) drain before the barrier (never fragile).
// Structure, dataflow and relaxed-atomic grid barrier identical to R5
// (passed, 9.4 ms) minus the two __threadfence() L2 walks.

typedef __bf16 bf16x8 __attribute__((ext_vector_type(8)));
typedef __bf16 bf16x4 __attribute__((ext_vector_type(4)));
typedef float  f32x4  __attribute__((ext_vector_type(4)));
typedef int    i32x4  __attribute__((ext_vector_type(4)));

constexpr int NB = 64;    // batch
constexpr int NT = 256;   // time
constexpr int ND = 1024;  // embed dim
constexpr int NH = 1024;  // hidden
constexpr int NL = 4;     // layers
constexpr int NG = 4096;  // 4*NH gate rows

// ---- LLC-coherent loads: one asm bundle, data VALID at asm exit ----------
__device__ __forceinline__ void ld4_b128_sc_sync(
    const void* p0, const void* p1, const void* p2, const void* p3,
    i32x4& r0, i32x4& r1, i32x4& r2, i32x4& r3)
{
    asm volatile(
        "global_load_dwordx4 %0, %4, off sc0 sc1\n\t"
        "global_load_dwordx4 %1, %5, off sc0 sc1\n\t"
        "global_load_dwordx4 %2, %6, off sc0 sc1\n\t"
        "global_load_dwordx4 %3, %7, off sc0 sc1\n\t"
        "s_waitcnt vmcnt(0)"
        : "=&v"(r0), "=&v"(r1), "=&v"(r2), "=&v"(r3)
        : "v"(p0), "v"(p1), "v"(p2), "v"(p3)
        : "memory");
}
// ---- LLC-coherent stores: fire-and-forget (inputs read at issue) ---------
__device__ __forceinline__ void st_b16_sc(void* p, float v) {
    unsigned b = (unsigned)__builtin_bit_cast(unsigned short, (__bf16)v);
    asm volatile("global_store_short %0, %1, off sc0 sc1" :: "v"(p), "v"(b) : "memory");
}
__device__ __forceinline__ void st_f32_sc(void* p, float v) {
    asm volatile("global_store_dword %0, %1, off sc0 sc1" :: "v"(p), "v"(v) : "memory");
}

// ---------------------------------------------------------------------------
// Persistent kernel. Grid: 4 layers x 64 cb = 256 blocks (1/CU, forced by
// 128 KB LDS). Block: 512 threads = 8 waves. Wave w: mat = w>>2 (0: Wih,
// 1: Whh), k0 = (w&3)*256 (K-slice). Weight regs: bf16x8 wreg[4 gates][8 ch].
// Per step, per dir: acc[4 m][4 n] over M=64 batch x N=64 gate-cols,
// partials -> gbuf[w][gate][col16][row64 ^ swz] -> pointwise LSTM.
// C/D frag (m89): row(batch)=(l>>4)*4+r (+16m), col=l&15.
// Barrier layout (uint idx): leaves at 32*(bid&15), root at 512, rel at 544.
// ---------------------------------------------------------------------------
__global__ __launch_bounds__(512, 2) void k_lstm(
    const __bf16* __restrict__ xbf,     // [NT][NB][ND]
    const __bf16* __restrict__ Wih,     // [NL][NG][ND] bf16
    const __bf16* __restrict__ Whh,     // [NL][NG][NH] bf16
    const float*  __restrict__ biasc,   // [NL][NG] (b_ih+b_hh)
    __bf16* __restrict__ ring_b,        // [2*NL][2][NB][NH] layer input (bf16)
    float*  __restrict__ ring_f,        // [2*NL][2][NB][NH] layer input (f32)
    __bf16* __restrict__ hbuf,          // [2*NL][2][NB][NH] h ping-pong
    __bf16* __restrict__ outcat,        // [NT][NB][2*NH]
    __bf16* __restrict__ hcat,          // [NL*NB][2*NH] final h
    __bf16* __restrict__ ccat,          // [NL*NB][2*NH] final c
    unsigned* __restrict__ bar)         // barrier state (zeroed per launch)
{
    const int layer = blockIdx.x >> 6;   // 0..3
    const int cb    = blockIdx.x & 63;   // 16 H-cols each
    const int tid   = threadIdx.x;
    const int w     = tid >> 6;          // 0..7
    const int mat   = w >> 2;            // 0: x-part (Wih), 1: h-part (Whh)
    const int k0    = (w & 3) * 256;     // K-slice within the 1024 of this mat
    const int lane  = tid & 63;
    const int lrow  = lane & 15;
    const int lk    = (lane >> 4) << 3;
    const int g4r   = (lane >> 4) << 2;  // row base within 16-row frag
    const size_t bh = (size_t)NB * NH;

    // --- persistent weights: 64 rows x 256 K bf16 = 128 VGPRs/wave ---
    bf16x8 wreg[4][8];
    {
        const __bf16* Bp = (mat ? Whh : Wih)
            + ((size_t)layer * NG + cb * 16 + lrow) * 1024 + k0 + lk;
        #pragma unroll
        for (int n = 0; n < 4; ++n)
            #pragma unroll
            for (int ch = 0; ch < 8; ++ch)
                wreg[n][ch] = *(const bf16x8*)(Bp + (size_t)n * NH * 1024 + ch * 32);
    }

    // --- per-thread persistent bias (n = tid&15 is this thread's col) ---
    float bias4[4];
    #pragma unroll
    for (int g = 0; g < 4; ++g)
        bias4[g] = biasc[(size_t)layer * NG + g * NH + cb * 16 + (tid & 15)];

    // --- per-thread persistent c state: [d][half], static mapping ---
    float c00 = 0.f, c01 = 0.f, c10 = 0.f, c11 = 0.f;

    // transposed partial buffer: [wave][gate][col16][row64], rows XOR-swizzled
    __shared__ __align__(16) float gbuf[8][4][16][64];   // 128 KB

    unsigned* leaf = bar + 32 * (blockIdx.x & 15);
    unsigned* root = bar + 512;
    unsigned* rel  = bar + 544;

    for (int gs = 0; gs < NT + NL - 1; ++gs) {
        const int tau = gs - layer;
        if (tau >= 0 && tau < NT) {
            #pragma unroll 1
            for (int d = 0; d < 2; ++d) {
                const int tt = d ? NT - 1 - tau : tau;
                const size_t ul = (size_t)(d * NL + layer);

                const bool cached_x = (mat == 0 && layer == 0);
                const __bf16* Ap;
                if (mat == 0)
                    Ap = (layer == 0) ? (xbf + (size_t)tt * NB * ND)
                                      : (ring_b + (ul * 2 + (tau & 1)) * bh);
                else
                    Ap = hbuf + (ul * 2 + ((tau + 1) & 1)) * bh;
                Ap += (size_t)lrow * 1024 + k0 + lk;

                f32x4 acc[4][4] = {};   // [m][gate]
                if (cached_x) {
                    // read-only xbf: normal cached loads, compiler-scheduled
                    #pragma unroll
                    for (int ch = 0; ch < 8; ++ch) {
                        bf16x8 av[4];
                        #pragma unroll
                        for (int m = 0; m < 4; ++m)
                            av[m] = *(const bf16x8*)(Ap + (size_t)m * 16384 + ch * 32);
                        #pragma unroll
                        for (int n = 0; n < 4; ++n)
                            #pragma unroll
                            for (int m = 0; m < 4; ++m)
                                acc[m][n] = __builtin_amdgcn_mfma_f32_16x16x32_bf16(
                                    av[m], wreg[n][ch], acc[m][n], 0, 0, 0);
                    }
                } else {
                    // LLC-coherent A: per-chunk synchronous 4-load bundle
                    #pragma unroll
                    for (int ch = 0; ch < 8; ++ch) {
                        i32x4 av[4];
                        const __bf16* base = Ap + ch * 32;
                        ld4_b128_sc_sync(base, base + 16384, base + 32768,
                                         base + 49152,
                                         av[0], av[1], av[2], av[3]);
                        #pragma unroll
                        for (int n = 0; n < 4; ++n)
                            #pragma unroll
                            for (int m = 0; m < 4; ++m)
                                acc[m][n] = __builtin_amdgcn_mfma_f32_16x16x32_bf16(
                                    __builtin_bit_cast(bf16x8, av[m]),
                                    wreg[n][ch], acc[m][n], 0, 0, 0);
                    }
                }

                // partials -> LDS as f32x4 (4 consecutive batch rows), swizzled
                #pragma unroll
                for (int n = 0; n < 4; ++n)
                    #pragma unroll
                    for (int m = 0; m < 4; ++m) {
                        const int row = (m * 16 + g4r) ^ ((lrow & 7) << 2);
                        *(f32x4*)&gbuf[w][n][lrow][row] = acc[m][n];
                    }
                __syncthreads();

                // fused LSTM pointwise: 2 cells/thread (n fixed = tid&15)
                {
                    const int n_  = tid & 15;
                    const int col = cb * 16 + n_;
                    const int b0r = tid >> 4;          // half-0 batch row
                    const int b1r = 32 + (tid >> 4);   // half-1 batch row
                    const size_t rbase = (ul * 2 + (tau & 1)) * bh;

                    // residual inputs (compiler-tracked sc loads / cached xbf)
                    float inp0, inp1;
                    if (layer == 0) {
                        inp0 = (float)xbf[(size_t)tt * NB * ND + (size_t)b0r * ND + col];
                        inp1 = (float)xbf[(size_t)tt * NB * ND + (size_t)b1r * ND + col];
                    } else {
                        inp0 = __hip_atomic_load(ring_f + rbase + (size_t)b0r * NH + col,
                                                 __ATOMIC_RELAXED, __HIP_MEMORY_SCOPE_SYSTEM);
                        inp1 = __hip_atomic_load(ring_f + rbase + (size_t)b1r * NH + col,
                                                 __ATOMIC_RELAXED, __HIP_MEMORY_SCOPE_SYSTEM);
                    }

                    const int swb0 = b0r ^ ((n_ & 7) << 2);
                    const int swb1 = b1r ^ ((n_ & 7) << 2);
                    float g0[4], g1[4];
                    #pragma unroll
                    for (int g = 0; g < 4; ++g) {
                        float s0 = bias4[g], s1 = bias4[g];
                        #pragma unroll
                        for (int q = 0; q < 8; ++q) {
                            s0 += gbuf[q][g][n_][swb0];
                            s1 += gbuf[q][g][n_][swb1];
                        }
                        g0[g] = s0; g1[g] = s1;
                    }
                    const float cp0 = d ? c10 : c00;
                    const float cp1 = d ? c11 : c01;
                    const float si0 = 1.f / (1.f + __expf(-g0[0]));
                    const float sf0 = 1.f / (1.f + __expf(-g0[1]));
                    const float so0 = 1.f / (1.f + __expf(-g0[3]));
                    const float tg0 = tanhf(g0[2]);
                    const float cn0 = sf0 * cp0 + si0 * tg0;
                    const float hn0 = so0 * tanhf(cn0);
                    const float si1 = 1.f / (1.f + __expf(-g1[0]));
                    const float sf1 = 1.f / (1.f + __expf(-g1[1]));
                    const float so1 = 1.f / (1.f + __expf(-g1[3]));
                    const float tg1 = tanhf(g1[2]);
                    const float cn1 = sf1 * cp1 + si1 * tg1;
                    const float hn1 = so1 * tanhf(cn1);
                    if (d) { c10 = cn0; c11 = cn1; }
                    else   { c00 = cn0; c01 = cn1; }

                    st_b16_sc(hbuf + rbase + (size_t)b0r * NH + col, hn0);
                    st_b16_sc(hbuf + rbase + (size_t)b1r * NH + col, hn1);
                    const float nv0 = inp0 + hn0;
                    const float nv1 = inp1 + hn1;
                    if (layer < NL - 1) {
                        const size_t r0 = ((ul + 1) * 2 + (tau & 1)) * bh + (size_t)b0r * NH + col;
                        const size_t r1 = ((ul + 1) * 2 + (tau & 1)) * bh + (size_t)b1r * NH + col;
                        st_f32_sc(ring_f + r0, nv0);
                        st_b16_sc(ring_b + r0, nv0);
                        st_f32_sc(ring_f + r1, nv1);
                        st_b16_sc(ring_b + r1, nv1);
                    } else {
                        st_b16_sc(outcat + ((size_t)tt * NB + b0r) * 2048 + (size_t)d * NH + col, nv0);
                        st_b16_sc(outcat + ((size_t)tt * NB + b1r) * 2048 + (size_t)d * NH + col, nv1);
                    }
                    if (tau == NT - 1) {
                        const size_t f0 = ((size_t)layer * NB + b0r) * 2048 + (size_t)d * NH + col;
                        const size_t f1 = ((size_t)layer * NB + b1r) * 2048 + (size_t)d * NH + col;
                        st_b16_sc(hcat + f0, hn0);
                        st_b16_sc(ccat + f0, cn0);
                        st_b16_sc(hcat + f1, hn1);
                        st_b16_sc(ccat + f1, cn1);
                    }
                }
                asm volatile("s_waitcnt vmcnt(0)" ::: "memory");  // drain sc stores
                __syncthreads();
            }
        }

        // ---- fence-free grid barrier (skip after last step) ----
        if (gs < NT + NL - 2) {
            __syncthreads();
            if (tid == 0) {
                const unsigned e1 = (unsigned)(gs + 1);
                const unsigned old = __hip_atomic_fetch_add(
                    leaf, 1u, __ATOMIC_RELAXED, __HIP_MEMORY_SCOPE_AGENT);
                if (old == 16u * e1 - 1u) {
                    const unsigned r = __hip_atomic_fetch_add(
                        root, 1u, __ATOMIC_RELAXED, __HIP_MEMORY_SCOPE_AGENT);
                    if (r == 16u * e1 - 1u)
                        __hip_atomic_store(rel, e1, __ATOMIC_RELAXED,
                                           __HIP_MEMORY_SCOPE_AGENT);
                }
                while (__hip_atomic_load(rel, __ATOMIC_RELAXED,
                                         __HIP_MEMORY_SCOPE_AGENT) < e1)
                    __builtin_amdgcn_s_sleep(2);
            }
            __syncthreads();
        }
    }
}

// ---------------------------------------------------------------------------
// Projection GEMM: Dst = A[M][2048] @ W[1024][2048]^T + bias.
// mode 0: A rows are (t*NB+b), write Dst[(b*NT+t)*NH + col]. mode 1: direct.
// ---------------------------------------------------------------------------
__global__ __launch_bounds__(256) void k_proj(
    const __bf16* __restrict__ A, const __bf16* __restrict__ W,
    const float* __restrict__ bias, float* __restrict__ Dst,
    int M, int mode)
{
    const int nblk = blockIdx.x & 15;
    const int mblk = blockIdx.x >> 4;
    const int tid  = threadIdx.x;
    const int w    = tid >> 6;
    const int lane = tid & 63;
    const int lrow = lane & 15;
    const int lk   = (lane >> 4) << 3;
    const int n0   = nblk * 64 + w * 16;
    const int m0   = mblk * 64;

    f32x4 acc[4] = {};
    #pragma unroll 2
    for (int k0 = 0; k0 < 2048; k0 += 32) {
        const int kc = k0 + lk;
        const bf16x8 bv = *(const bf16x8*)(W + (size_t)(n0 + lrow) * 2048 + kc);
        #pragma unroll
        for (int m = 0; m < 4; ++m) {
            const bf16x8 av = *(const bf16x8*)(A + (size_t)(m0 + m * 16 + lrow) * 2048 + kc);
            acc[m] = __builtin_amdgcn_mfma_f32_16x16x32_bf16(av, bv, acc[m], 0, 0, 0);
        }
    }
    #pragma unroll
    for (int m = 0; m < 4; ++m) {
        #pragma unroll
        for (int r = 0; r < 4; ++r) {
            const int row = m0 + m * 16 + ((lane >> 4) << 2) + r;
            const int col = n0 + lrow;
            const float v = acc[m][r] + bias[col];
            if (mode == 0) {
                const int tt = row >> 6, bb = row & 63;
                Dst[((size_t)bb * NT + tt) * NH + col] = v;
            } else {
                Dst[(size_t)row * NH + col] = v;
            }
        }
    }
}

__global__ void k_embed(const int* __restrict__ enc, const float* __restrict__ emb,
                        __bf16* __restrict__ xbf)
{
    const int r = blockIdx.x;          // t*NB + b
    const int t = r >> 6;
    const int b = r & 63;
    const int id = enc[b * NT + t];
    const float4 v = ((const float4*)(emb + (size_t)id * ND))[threadIdx.x];
    bf16x4 o;
    o[0] = (__bf16)v.x; o[1] = (__bf16)v.y; o[2] = (__bf16)v.z; o[3] = (__bf16)v.w;
    ((bf16x4*)(xbf + (size_t)r * ND))[threadIdx.x] = o;
}

__global__ void k_cvt(const float* __restrict__ src, __bf16* __restrict__ dst, size_t n4)
{
    size_t i = (size_t)blockIdx.x * blockDim.x + threadIdx.x;
    const size_t stride = (size_t)gridDim.x * blockDim.x;
    for (; i < n4; i += stride) {
        const float4 v = ((const float4*)src)[i];
        bf16x4 o;
        o[0] = (__bf16)v.x; o[1] = (__bf16)v.y; o[2] = (__bf16)v.z; o[3] = (__bf16)v.w;
        ((bf16x4*)dst)[i] = o;
    }
}

__global__ void k_bias(const float* __restrict__ a, const float* __restrict__ b,
                       float* __restrict__ o, int n)
{
    const int i = blockIdx.x * blockDim.x + threadIdx.x;
    if (i < n) o[i] = a[i] + b[i];
}

extern "C" void kernel_launch(void* const* d_in, const int* in_sizes, int n_in,
                              void* d_out, int out_size, void* d_ws, size_t ws_size,
                              hipStream_t stream)
{
    const int*   enc   = (const int*)  d_in[0];
    const float* emb   = (const float*)d_in[1];
    const float* Wih_f = (const float*)d_in[2];
    const float* Whh_f = (const float*)d_in[3];
    const float* bih   = (const float*)d_in[4];
    const float* bhh   = (const float*)d_in[5];
    const float* Wo_f  = (const float*)d_in[6];
    const float* bo    = (const float*)d_in[7];
    const float* Wh_f  = (const float*)d_in[8];
    const float* bh    = (const float*)d_in[9];
    const float* Wc_f  = (const float*)d_in[10];
    const float* bc    = (const float*)d_in[11];
    float* out = (float*)d_out;

    char* ws = (char*)d_ws;
    size_t off = 0;
    auto alloc = [&](size_t bytes) -> char* {
        off = (off + 255) & ~(size_t)255;
        char* p = ws + off;
        off += bytes;
        return p;
    };
    __bf16* Wih_b  = (__bf16*)alloc((size_t)NL * NG * ND * 2);
    __bf16* Whh_b  = (__bf16*)alloc((size_t)NL * NG * NH * 2);
    __bf16* Wo_b   = (__bf16*)alloc((size_t)NH * 2 * NH * 2);
    __bf16* Wh_b   = (__bf16*)alloc((size_t)NH * 2 * NH * 2);
    __bf16* Wc_b   = (__bf16*)alloc((size_t)NH * 2 * NH * 2);
    float*  biasc  = (float*) alloc((size_t)NL * NG * 4);
    __bf16* xbf    = (__bf16*)alloc((size_t)NT * NB * ND * 2);
    __bf16* ring_b = (__bf16*)alloc((size_t)2 * NL * 2 * NB * NH * 2);
    float*  ring_f = (float*) alloc((size_t)2 * NL * 2 * NB * NH * 4);
    __bf16* hbuf   = (__bf16*)alloc((size_t)2 * NL * 2 * NB * NH * 2);
    __bf16* outcat = (__bf16*)alloc((size_t)NT * NB * 2 * NH * 2);
    __bf16* hcat   = (__bf16*)alloc((size_t)NL * NB * 2 * NH * 2);
    __bf16* ccat   = (__bf16*)alloc((size_t)NL * NB * 2 * NH * 2);
    unsigned* bar  = (unsigned*)alloc(4096);

    auto launch_cvt = [&](const float* s, __bf16* d, size_t n) {
        size_t n4 = n / 4;
        int blocks = (int)((n4 + 255) / 256);
        if (blocks > 2048) blocks = 2048;
        k_cvt<<<blocks, 256, 0, stream>>>(s, d, n4);
    };
    launch_cvt(Wih_f, Wih_b, (size_t)NL * NG * ND);
    launch_cvt(Whh_f, Whh_b, (size_t)NL * NG * NH);
    launch_cvt(Wo_f,  Wo_b,  (size_t)2 * NH * NH);
    launch_cvt(Wh_f,  Wh_b,  (size_t)2 * NH * NH);
    launch_cvt(Wc_f,  Wc_b,  (size_t)2 * NH * NH);
    k_bias<<<(NL * NG) / 256, 256, 0, stream>>>(bih, bhh, biasc, NL * NG);
    k_embed<<<NT * NB, 256, 0, stream>>>(enc, emb, xbf);
    // h state + barrier counters must be zeroed EVERY launch (graph replays
    // leave final state; barrier epochs are monotonic within one launch).
    hipMemsetAsync(hbuf, 0, (size_t)2 * NL * 2 * NB * NH * 2, stream);
    hipMemsetAsync(bar, 0, 4096, stream);

    void* kargs[] = {
        (void*)&xbf, (void*)&Wih_b, (void*)&Whh_b, (void*)&biasc,
        (void*)&ring_b, (void*)&ring_f, (void*)&hbuf,
        (void*)&outcat, (void*)&hcat, (void*)&ccat, (void*)&bar };
    hipLaunchCooperativeKernel((const void*)k_lstm, dim3(256), dim3(512),
                               kargs, 0, stream);

    k_proj<<<(NT * NB / 64) * 16, 256, 0, stream>>>(outcat, Wo_b, bo, out, NT * NB, 0);
    k_proj<<<(NL * NB / 64) * 16, 256, 0, stream>>>(hcat, Wh_b, bh,
        out + (size_t)NB * NT * NH, NL * NB, 1);
    k_proj<<<(NL * NB / 64) * 16, 256, 0, stream>>>(ccat, Wc_b, bc,
        out + (size_t)NB * NT * NH + (size_t)NL * NB * NH, NL * NB, 1);
}